// Round 3
// baseline (399.179 us; speedup 1.0000x reference)
//
#include <hip/hip_runtime.h>
#include <math.h>

typedef __bf16 bf16_t;
typedef bf16_t bf16x8 __attribute__((ext_vector_type(8)));
typedef float  f32x4  __attribute__((ext_vector_type(4)));

#define PI_F 3.14159265358979323846f

constexpr int H = 64, W = 64, Q = 65536;
constexpr int C = 256, CF = 128;
constexpr int QPB = 16;        // queries per block (was 32 -> halve LDS, double blocks)
constexpr int ROWS = QPB * 4;  // 64 rows
constexpr int PADC = 260;      // row stride: 520B -> 4-row stride = 520 dw = 8 mod 32 (spread banks)

// ---------------- prep kernels ----------------

// src [Crows][4096] -> dst [4096][Crows]
__global__ void transpose_kernel(const float* __restrict__ src, float* __restrict__ dst, int Crows) {
    __shared__ float tile[32][33];
    int bx = blockIdx.x * 32;  // pixel dim
    int by = blockIdx.y * 32;  // channel dim
    int tx = threadIdx.x & 31;
    int ty = threadIdx.x >> 5;  // 0..7
#pragma unroll
    for (int i = 0; i < 4; i++) {
        tile[ty + i * 8][tx] = src[(by + ty + i * 8) * 4096 + bx + tx];
    }
    __syncthreads();
#pragma unroll
    for (int i = 0; i < 4; i++) {
        dst[(bx + ty + i * 8) * Crows + by + tx] = tile[tx][ty + i * 8];
    }
}

__global__ void cvt_w_kernel(const float* __restrict__ w1, const float* __restrict__ w2,
                             bf16_t* __restrict__ w1b, bf16_t* __restrict__ w2b) {
    int i = blockIdx.x * 256 + threadIdx.x;  // 65536 total
    w1b[i] = (bf16_t)w1[i];
    w2b[i] = (bf16_t)w2[i];
}

// pack (wcf[k][0], wcf[k][1], wph[k][0], wph[k][1]) -> one float4 per k
__global__ void pack_tab_kernel(const float* __restrict__ wcf, const float* __restrict__ wph,
                                float4* __restrict__ wtab) {
    int k = threadIdx.x;  // 128
    float4 v;
    v.x = wcf[k * 2 + 0]; v.y = wcf[k * 2 + 1];
    v.z = wph[k * 2 + 0]; v.w = wph[k * 2 + 1];
    wtab[k] = v;
}

// ---------------- fused main kernel ----------------

__global__ __launch_bounds__(512, 4)
void lte_fused_kernel(const float* __restrict__ coefT,   // [4096][256]
                      const float* __restrict__ freqT,   // [4096][128]
                      const bf16_t* __restrict__ w1b,    // [256][256] (out,in)
                      const bf16_t* __restrict__ w2b,
                      const float4* __restrict__ wtab,   // [128] packed (wcf0,wcf1,wph0,wph1)
                      const float* __restrict__ img,     // [3][64][64]
                      const float* __restrict__ coord,   // [Q][2]
                      const float* __restrict__ cell,    // [Q][2]
                      const float* __restrict__ b1,
                      const float* __restrict__ b2,
                      const float* __restrict__ w3,      // [3][256]
                      const float* __restrict__ b3,
                      float* __restrict__ out)           // [Q][3]
{
    extern __shared__ char smem[];
    bf16_t* buf    = (bf16_t*)smem;              // [64][260] bf16: X -> h1 -> h2 (33280 B)
    float*  w3s    = (float*)(smem + 33280);     // [3][256] (3072 B)
    float*  areaS  = (float*)(smem + 36352);     // [64]
    float*  predsS = (float*)(smem + 36608);     // [64][3]

    const int t    = threadIdx.x;
    const int lane = t & 63;
    const int wv   = t >> 6;     // wave id 0..7 -> 32-col stripe
    const int l15  = lane & 15;
    const int l16  = lane >> 4;

    for (int i = t; i < 768; i += 512) w3s[i] = w3[i];

    // ---- stage 1: features -> X (bf16) in LDS. 8 threads per row, 16 k each ----
    {
        const int row = t >> 3;   // 0..63
        const int t8  = t & 7;
        const int qL  = row >> 2;
        const int o   = row & 3;
        const int q   = blockIdx.x * QPB + qL;
        const float c0  = coord[q * 2 + 0];
        const float c1  = coord[q * 2 + 1];
        const float rc0 = cell[q * 2 + 0] * (float)H;
        const float rc1 = cell[q * 2 + 1] * (float)W;
        const float vx = (o & 2) ? 1.f : -1.f;
        const float vy = (o & 1) ? 1.f : -1.f;
        const float EPS = 1e-6f;
        float g0 = fminf(fmaxf(c0 + vx * (1.f / H) + EPS, -1.f + EPS), 1.f - EPS);
        float g1 = fminf(fmaxf(c1 + vy * (1.f / W) + EPS, -1.f + EPS), 1.f - EPS);
        int iy = (int)floorf(((g0 + 1.f) * (float)H - 1.f) * 0.5f + 0.5f);
        iy = min(max(iy, 0), H - 1);
        int ix = (int)floorf(((g1 + 1.f) * (float)W - 1.f) * 0.5f + 0.5f);
        ix = min(max(ix, 0), W - 1);
        const float rel0 = (c0 - (-1.f + (2.f * (float)iy + 1.f) / (float)H)) * (float)H;
        const float rel1 = (c1 - (-1.f + (2.f * (float)ix + 1.f) / (float)W)) * (float)W;
        if (t8 == 0) areaS[row] = fabsf(rel0 * rel1) + 1e-9f;
        const int pix = iy * W + ix;
        const float* fq = freqT + pix * CF;
        const float* cf = coefT + pix * C;
#pragma unroll
        for (int c8 = 0; c8 < 2; c8++) {
            const int kb = t8 * 16 + c8 * 8;
            const float4 f0  = *(const float4*)(fq + kb);
            const float4 f1  = *(const float4*)(fq + kb + 4);
            const float4 cc0 = *(const float4*)(cf + kb);
            const float4 cc1 = *(const float4*)(cf + kb + 4);
            const float4 cs0 = *(const float4*)(cf + 128 + kb);
            const float4 cs1 = *(const float4*)(cf + 128 + kb + 4);
            float fv[8]  = {f0.x, f0.y, f0.z, f0.w, f1.x, f1.y, f1.z, f1.w};
            float cv[8]  = {cc0.x, cc0.y, cc0.z, cc0.w, cc1.x, cc1.y, cc1.z, cc1.w};
            float sv[8]  = {cs0.x, cs0.y, cs0.z, cs0.w, cs1.x, cs1.y, cs1.z, cs1.w};
            bf16x8 vc, vs;
#pragma unroll
            for (int j = 0; j < 8; j++) {
                const int k = kb + j;
                const float4 tv = wtab[k];
                const float proj = rel0 * tv.x + rel1 * tv.y;
                const float ph   = rc0 * tv.z + rc1 * tv.w;
                const float m = fv[j] * proj + ph;
                float s, cst;
                __sincosf(PI_F * m, &s, &cst);
                vc[j] = (bf16_t)(cv[j] * cst);
                vs[j] = (bf16_t)(sv[j] * s);
            }
            *(bf16x8*)(buf + row * PADC + kb)       = vc;
            *(bf16x8*)(buf + row * PADC + 128 + kb) = vs;
        }
    }
    __syncthreads();

    // ---- layers 1 & 2: MFMA. 8 waves; wave = all 64 rows x 32-col stripe ----
#pragma unroll 1
    for (int layer = 0; layer < 2; layer++) {
        const bf16_t* Wg = (layer == 0) ? w1b : w2b;
        const float*  bg = (layer == 0) ? b1 : b2;
        f32x4 acc[4][2];
#pragma unroll
        for (int mi = 0; mi < 4; mi++)
#pragma unroll
            for (int nf = 0; nf < 2; nf++) {
                f32x4 z = {0.f, 0.f, 0.f, 0.f};
                acc[mi][nf] = z;
            }
#pragma unroll
        for (int kb = 0; kb < 8; kb++) {
            bf16x8 a[4];
#pragma unroll
            for (int mi = 0; mi < 4; mi++)
                a[mi] = *(bf16x8*)(buf + (mi * 16 + l15) * PADC + kb * 32 + l16 * 8);
            bf16x8 bfr[2];
#pragma unroll
            for (int nf = 0; nf < 2; nf++) {
                const int n = wv * 32 + nf * 16 + l15;
                bfr[nf] = *(const bf16x8*)(Wg + n * 256 + kb * 32 + l16 * 8);
            }
#pragma unroll
            for (int mi = 0; mi < 4; mi++)
#pragma unroll
                for (int nf = 0; nf < 2; nf++)
                    acc[mi][nf] = __builtin_amdgcn_mfma_f32_16x16x32_bf16(a[mi], bfr[nf], acc[mi][nf], 0, 0, 0);
        }
        __syncthreads();  // all reads of buf done
#pragma unroll
        for (int nf = 0; nf < 2; nf++) {
            const int col = wv * 32 + nf * 16 + l15;
            const float bv = bg[col];
#pragma unroll
            for (int mi = 0; mi < 4; mi++)
#pragma unroll
                for (int r = 0; r < 4; r++) {
                    const int row = mi * 16 + l16 * 4 + r;
                    float v = acc[mi][nf][r] + bv;
                    v = fmaxf(v, 0.f);  // relu
                    buf[row * PADC + col] = (bf16_t)v;
                }
        }
        __syncthreads();
    }

    // ---- layer 3: 8 threads/row, 32 cols each, shuffle reduce ----
    {
        const int row = t >> 3;
        const int t8  = t & 7;
        float p0 = 0.f, p1 = 0.f, p2 = 0.f;
#pragma unroll
        for (int c8 = 0; c8 < 4; c8++) {
            const int c = t8 * 32 + c8 * 8;
            bf16x8 hv = *(bf16x8*)(buf + row * PADC + c);
#pragma unroll
            for (int j = 0; j < 8; j++) {
                const float h = (float)hv[j];
                p0 = fmaf(h, w3s[c + j], p0);
                p1 = fmaf(h, w3s[256 + c + j], p1);
                p2 = fmaf(h, w3s[512 + c + j], p2);
            }
        }
        p0 += __shfl_xor(p0, 1); p0 += __shfl_xor(p0, 2); p0 += __shfl_xor(p0, 4);
        p1 += __shfl_xor(p1, 1); p1 += __shfl_xor(p1, 2); p1 += __shfl_xor(p1, 4);
        p2 += __shfl_xor(p2, 1); p2 += __shfl_xor(p2, 2); p2 += __shfl_xor(p2, 4);
        if (t8 == 0) {
            predsS[row * 3 + 0] = p0 + b3[0];
            predsS[row * 3 + 1] = p1 + b3[1];
            predsS[row * 3 + 2] = p2 + b3[2];
        }
    }
    __syncthreads();

    // ---- combine: area weights (reversed) + bilinear border sample ----
    if (t < QPB) {
        const int qL = t;
        const int q  = blockIdx.x * QPB + qL;
        const int r0 = qL * 4;
        const float a0 = areaS[r0 + 0], a1 = areaS[r0 + 1], a2 = areaS[r0 + 2], a3 = areaS[r0 + 3];
        const float inv = 1.f / (a0 + a1 + a2 + a3);
        const float wgt0 = a3 * inv, wgt1 = a2 * inv, wgt2 = a1 * inv, wgt3 = a0 * inv;
        const float c0 = coord[q * 2 + 0];
        const float c1 = coord[q * 2 + 1];
        float gy = fminf(fmaxf(((c0 + 1.f) * (float)H - 1.f) * 0.5f, 0.f), (float)(H - 1));
        float gx = fminf(fmaxf(((c1 + 1.f) * (float)W - 1.f) * 0.5f, 0.f), (float)(W - 1));
        int y0 = (int)floorf(gy); int x0 = (int)floorf(gx);
        int y1 = min(y0 + 1, H - 1); int x1 = min(x0 + 1, W - 1);
        const float wy = gy - (float)y0, wx = gx - (float)x0;
#pragma unroll
        for (int ch = 0; ch < 3; ch++) {
            const float ret = predsS[(r0 + 0) * 3 + ch] * wgt0 + predsS[(r0 + 1) * 3 + ch] * wgt1
                            + predsS[(r0 + 2) * 3 + ch] * wgt2 + predsS[(r0 + 3) * 3 + ch] * wgt3;
            const float* ip = img + ch * 4096;
            const float v00 = ip[y0 * 64 + x0], v01 = ip[y0 * 64 + x1];
            const float v10 = ip[y1 * 64 + x0], v11 = ip[y1 * 64 + x1];
            const float samp = v00 * (1.f - wy) * (1.f - wx) + v01 * (1.f - wy) * wx
                             + v10 * wy * (1.f - wx) + v11 * wy * wx;
            out[q * 3 + ch] = ret + samp;
        }
    }
}

// ---------------- launch ----------------

extern "C" void kernel_launch(void* const* d_in, const int* in_sizes, int n_in,
                              void* d_out, int out_size, void* d_ws, size_t ws_size,
                              hipStream_t stream) {
    const float* img   = (const float*)d_in[0];
    const float* coef  = (const float*)d_in[1];
    const float* freq  = (const float*)d_in[2];
    const float* coord = (const float*)d_in[3];
    const float* cell  = (const float*)d_in[4];
    const float* wcf   = (const float*)d_in[5];
    const float* wph   = (const float*)d_in[6];
    const float* w1    = (const float*)d_in[7];
    const float* b1    = (const float*)d_in[8];
    const float* w2    = (const float*)d_in[9];
    const float* b2    = (const float*)d_in[10];
    const float* w3    = (const float*)d_in[11];
    const float* b3    = (const float*)d_in[12];
    float* out = (float*)d_out;

    char* ws = (char*)d_ws;
    float*  coefT = (float*)ws;                   // 4,194,304
    float*  freqT = (float*)(ws + 4194304);       // 2,097,152
    bf16_t* w1b   = (bf16_t*)(ws + 6291456);      // 131,072
    bf16_t* w2b   = (bf16_t*)(ws + 6422528);      // 131,072
    float4* wtab  = (float4*)(ws + 6553600);      // 2,048

    transpose_kernel<<<dim3(128, 8), 256, 0, stream>>>(coef, coefT, 256);
    transpose_kernel<<<dim3(128, 4), 256, 0, stream>>>(freq, freqT, 128);
    cvt_w_kernel<<<256, 256, 0, stream>>>(w1, w2, w1b, w2b);
    pack_tab_kernel<<<1, 128, 0, stream>>>(wcf, wph, wtab);

    const size_t ldsBytes = 37376;  // 33280 buf + 3072 w3 + 256 area + 768 preds
    lte_fused_kernel<<<Q / QPB, 512, ldsBytes, stream>>>(
        coefT, freqT, w1b, w2b, wtab, img, coord, cell, b1, b2, w3, b3, out);
}

// Round 4
// 194.019 us; speedup vs baseline: 2.0574x; 2.0574x over previous
//
#include <hip/hip_runtime.h>
#include <math.h>

typedef __bf16 bf16_t;
typedef bf16_t bf16x8 __attribute__((ext_vector_type(8)));
typedef float  f32x4  __attribute__((ext_vector_type(4)));

#define PI_F 3.14159265358979323846f

constexpr int H = 64, W = 64, Q = 65536;
constexpr int C = 256, CF = 128;
constexpr int QPB = 32;        // queries per block (round-2 geometry: 2048 blocks)
constexpr int ROWS = QPB * 4;  // 128 rows
constexpr int PADC = 264;      // LDS row stride (bf16): round-2 value

// ---------------- prep kernels ----------------

// src [Crows][4096] f32 -> dst [4096][Crows] bf16  (pixel-major, L2-resident gathers)
__global__ void transpose_cvt_kernel(const float* __restrict__ src, bf16_t* __restrict__ dst, int Crows) {
    __shared__ float tile[32][33];
    int bx = blockIdx.x * 32;  // pixel dim
    int by = blockIdx.y * 32;  // channel dim
    int tx = threadIdx.x & 31;
    int ty = threadIdx.x >> 5;  // 0..7
#pragma unroll
    for (int i = 0; i < 4; i++) {
        tile[ty + i * 8][tx] = src[(by + ty + i * 8) * 4096 + bx + tx];
    }
    __syncthreads();
#pragma unroll
    for (int i = 0; i < 4; i++) {
        dst[(bx + ty + i * 8) * Crows + by + tx] = (bf16_t)tile[tx][ty + i * 8];
    }
}

__global__ void cvt_w_kernel(const float* __restrict__ w1, const float* __restrict__ w2,
                             bf16_t* __restrict__ w1b, bf16_t* __restrict__ w2b) {
    int i = blockIdx.x * 256 + threadIdx.x;  // 65536 total
    w1b[i] = (bf16_t)w1[i];
    w2b[i] = (bf16_t)w2[i];
}

// pack (wcf[k][0], wcf[k][1], wph[k][0], wph[k][1]) -> one float4 per k
__global__ void pack_tab_kernel(const float* __restrict__ wcf, const float* __restrict__ wph,
                                float4* __restrict__ wtab) {
    int k = threadIdx.x;  // 128
    float4 v;
    v.x = wcf[k * 2 + 0]; v.y = wcf[k * 2 + 1];
    v.z = wph[k * 2 + 0]; v.w = wph[k * 2 + 1];
    wtab[k] = v;
}

// ---------------- fused main kernel ----------------

// load the wave's 2 B-fragments for k-block kb
#define LOADB(dst, Wptr, kb)                                                            \
    {                                                                                   \
        dst[0] = *(const bf16x8*)((Wptr) + (wv * 32 + l15) * 256 + (kb) * 32 + l16 * 8);      \
        dst[1] = *(const bf16x8*)((Wptr) + (wv * 32 + 16 + l15) * 256 + (kb) * 32 + l16 * 8); \
    }

__global__ __launch_bounds__(512, 4)
void lte_fused_kernel(const bf16_t* __restrict__ coefT,  // [4096][256] bf16
                      const bf16_t* __restrict__ freqT,  // [4096][128] bf16
                      const bf16_t* __restrict__ w1b,    // [256][256] (out,in)
                      const bf16_t* __restrict__ w2b,
                      const float4* __restrict__ wtab,   // [128] packed (wcf0,wcf1,wph0,wph1)
                      const float* __restrict__ img,     // [3][64][64]
                      const float* __restrict__ coord,   // [Q][2]
                      const float* __restrict__ cell,    // [Q][2]
                      const float* __restrict__ b1,
                      const float* __restrict__ b2,
                      const float* __restrict__ w3,      // [3][256]
                      const float* __restrict__ b3,
                      float* __restrict__ out)           // [Q][3]
{
    extern __shared__ char smem[];
    bf16_t* buf    = (bf16_t*)smem;              // [128][264] bf16: X -> h1 -> h2 (67584 B)
    float*  w3s    = (float*)(smem + 67584);     // [3][256]
    float*  areaS  = (float*)(smem + 70656);     // [128]
    float*  predsS = (float*)(smem + 71168);     // [128][3]

    const int t    = threadIdx.x;
    const int lane = t & 63;
    const int wv   = t >> 6;     // wave id 0..7 -> 32-col stripe
    const int l15  = lane & 15;
    const int l16  = lane >> 4;

    for (int i = t; i < 768; i += 512) w3s[i] = w3[i];

    // ---- stage 1: features -> X (bf16) in LDS. 4 threads/row, 32 k each ----
    {
        const int row = t >> 2;   // 0..127
        const int t4  = t & 3;
        const int qL  = row >> 2;
        const int o   = row & 3;
        const int q   = blockIdx.x * QPB + qL;
        const float c0  = coord[q * 2 + 0];
        const float c1  = coord[q * 2 + 1];
        const float rc0 = cell[q * 2 + 0] * (float)H;
        const float rc1 = cell[q * 2 + 1] * (float)W;
        const float vx = (o & 2) ? 1.f : -1.f;
        const float vy = (o & 1) ? 1.f : -1.f;
        const float EPS = 1e-6f;
        float g0 = fminf(fmaxf(c0 + vx * (1.f / H) + EPS, -1.f + EPS), 1.f - EPS);
        float g1 = fminf(fmaxf(c1 + vy * (1.f / W) + EPS, -1.f + EPS), 1.f - EPS);
        int iy = (int)floorf(((g0 + 1.f) * (float)H - 1.f) * 0.5f + 0.5f);
        iy = min(max(iy, 0), H - 1);
        int ix = (int)floorf(((g1 + 1.f) * (float)W - 1.f) * 0.5f + 0.5f);
        ix = min(max(ix, 0), W - 1);
        const float rel0 = (c0 - (-1.f + (2.f * (float)iy + 1.f) / (float)H)) * (float)H;
        const float rel1 = (c1 - (-1.f + (2.f * (float)ix + 1.f) / (float)W)) * (float)W;
        if (t4 == 0) areaS[row] = fabsf(rel0 * rel1) + 1e-9f;
        const int pix = iy * W + ix;
        const bf16_t* fq = freqT + pix * CF;
        const bf16_t* cf = coefT + pix * C;
        const int k0 = t4 * 32;

        // issue ALL gathers up front (12 x 16B); latency overlaps with wtab reads + trig
        bf16x8 fqv[4], ccv[4], csv[4];
#pragma unroll
        for (int i = 0; i < 4; i++) {
            fqv[i] = *(const bf16x8*)(fq + k0 + i * 8);
            ccv[i] = *(const bf16x8*)(cf + k0 + i * 8);
            csv[i] = *(const bf16x8*)(cf + 128 + k0 + i * 8);
        }
#pragma unroll
        for (int i = 0; i < 4; i++) {
            bf16x8 vc, vs;
#pragma unroll
            for (int j = 0; j < 8; j++) {
                const int k = k0 + i * 8 + j;
                const float4 tv = wtab[k];
                const float proj = rel0 * tv.x + rel1 * tv.y;
                const float ph   = rc0 * tv.z + rc1 * tv.w;
                const float m = (float)fqv[i][j] * proj + ph;
                float s, cst;
                __sincosf(PI_F * m, &s, &cst);
                vc[j] = (bf16_t)((float)ccv[i][j] * cst);
                vs[j] = (bf16_t)((float)csv[i][j] * s);
            }
            *(bf16x8*)(buf + row * PADC + k0 + i * 8)       = vc;
            *(bf16x8*)(buf + row * PADC + 128 + k0 + i * 8) = vs;
        }
    }

    // prefetch layer-1 B fragments for kb=0,1 BEFORE the barrier (independent of LDS)
    bf16x8 b1q[8][2];
    LOADB(b1q[0], w1b, 0);
    LOADB(b1q[1], w1b, 1);
    __syncthreads();

    // ---- layer 1: MFMA, wave = 128 rows x 32-col stripe, depth-2 B prefetch ----
    bf16x8 b2q[8][2];
    {
        f32x4 acc[8][2];
#pragma unroll
        for (int mi = 0; mi < 8; mi++)
#pragma unroll
            for (int nf = 0; nf < 2; nf++) {
                f32x4 z = {0.f, 0.f, 0.f, 0.f};
                acc[mi][nf] = z;
            }
#pragma unroll
        for (int kb = 0; kb < 8; kb++) {
            if (kb < 6) { LOADB(b1q[kb + 2], w1b, kb + 2); }
            bf16x8 a[8];
#pragma unroll
            for (int mi = 0; mi < 8; mi++)
                a[mi] = *(bf16x8*)(buf + (mi * 16 + l15) * PADC + kb * 32 + l16 * 8);
#pragma unroll
            for (int mi = 0; mi < 8; mi++)
#pragma unroll
                for (int nf = 0; nf < 2; nf++)
                    acc[mi][nf] = __builtin_amdgcn_mfma_f32_16x16x32_bf16(a[mi], b1q[kb][nf], acc[mi][nf], 0, 0, 0);
        }
        // prefetch layer-2 kb=0,1 before the barrier
        LOADB(b2q[0], w2b, 0);
        LOADB(b2q[1], w2b, 1);
        __syncthreads();  // all reads of X done
#pragma unroll
        for (int nf = 0; nf < 2; nf++) {
            const int col = wv * 32 + nf * 16 + l15;
            const float bv = b1[col];
#pragma unroll
            for (int mi = 0; mi < 8; mi++)
#pragma unroll
                for (int r = 0; r < 4; r++) {
                    const int row = mi * 16 + l16 * 4 + r;
                    buf[row * PADC + col] = (bf16_t)fmaxf(acc[mi][nf][r] + bv, 0.f);
                }
        }
        __syncthreads();
    }

    // ---- layer 2 ----
    {
        f32x4 acc[8][2];
#pragma unroll
        for (int mi = 0; mi < 8; mi++)
#pragma unroll
            for (int nf = 0; nf < 2; nf++) {
                f32x4 z = {0.f, 0.f, 0.f, 0.f};
                acc[mi][nf] = z;
            }
#pragma unroll
        for (int kb = 0; kb < 8; kb++) {
            if (kb < 6) { LOADB(b2q[kb + 2], w2b, kb + 2); }
            bf16x8 a[8];
#pragma unroll
            for (int mi = 0; mi < 8; mi++)
                a[mi] = *(bf16x8*)(buf + (mi * 16 + l15) * PADC + kb * 32 + l16 * 8);
#pragma unroll
            for (int mi = 0; mi < 8; mi++)
#pragma unroll
                for (int nf = 0; nf < 2; nf++)
                    acc[mi][nf] = __builtin_amdgcn_mfma_f32_16x16x32_bf16(a[mi], b2q[kb][nf], acc[mi][nf], 0, 0, 0);
        }
        __syncthreads();  // all reads of h1 done
#pragma unroll
        for (int nf = 0; nf < 2; nf++) {
            const int col = wv * 32 + nf * 16 + l15;
            const float bv = b2[col];
#pragma unroll
            for (int mi = 0; mi < 8; mi++)
#pragma unroll
                for (int r = 0; r < 4; r++) {
                    const int row = mi * 16 + l16 * 4 + r;
                    buf[row * PADC + col] = (bf16_t)fmaxf(acc[mi][nf][r] + bv, 0.f);
                }
        }
        __syncthreads();
    }

    // ---- layer 3: 4 threads/row, 64 cols each, shuffle reduce ----
    {
        const int row = t >> 2;
        const int t4  = t & 3;
        float p0 = 0.f, p1 = 0.f, p2 = 0.f;
#pragma unroll
        for (int c8 = 0; c8 < 8; c8++) {
            const int c = t4 * 64 + c8 * 8;
            bf16x8 hv = *(bf16x8*)(buf + row * PADC + c);
#pragma unroll
            for (int j = 0; j < 8; j++) {
                const float h = (float)hv[j];
                p0 = fmaf(h, w3s[c + j], p0);
                p1 = fmaf(h, w3s[256 + c + j], p1);
                p2 = fmaf(h, w3s[512 + c + j], p2);
            }
        }
        p0 += __shfl_xor(p0, 1); p0 += __shfl_xor(p0, 2);
        p1 += __shfl_xor(p1, 1); p1 += __shfl_xor(p1, 2);
        p2 += __shfl_xor(p2, 1); p2 += __shfl_xor(p2, 2);
        if (t4 == 0) {
            predsS[row * 3 + 0] = p0 + b3[0];
            predsS[row * 3 + 1] = p1 + b3[1];
            predsS[row * 3 + 2] = p2 + b3[2];
        }
    }
    __syncthreads();

    // ---- combine: area weights (reversed) + bilinear border sample ----
    if (t < QPB) {
        const int qL = t;
        const int q  = blockIdx.x * QPB + qL;
        const int r0 = qL * 4;
        const float a0 = areaS[r0 + 0], a1 = areaS[r0 + 1], a2 = areaS[r0 + 2], a3 = areaS[r0 + 3];
        const float inv = 1.f / (a0 + a1 + a2 + a3);
        const float wgt0 = a3 * inv, wgt1 = a2 * inv, wgt2 = a1 * inv, wgt3 = a0 * inv;
        const float c0 = coord[q * 2 + 0];
        const float c1 = coord[q * 2 + 1];
        float gy = fminf(fmaxf(((c0 + 1.f) * (float)H - 1.f) * 0.5f, 0.f), (float)(H - 1));
        float gx = fminf(fmaxf(((c1 + 1.f) * (float)W - 1.f) * 0.5f, 0.f), (float)(W - 1));
        int y0 = (int)floorf(gy); int x0 = (int)floorf(gx);
        int y1 = min(y0 + 1, H - 1); int x1 = min(x0 + 1, W - 1);
        const float wy = gy - (float)y0, wx = gx - (float)x0;
#pragma unroll
        for (int ch = 0; ch < 3; ch++) {
            const float ret = predsS[(r0 + 0) * 3 + ch] * wgt0 + predsS[(r0 + 1) * 3 + ch] * wgt1
                            + predsS[(r0 + 2) * 3 + ch] * wgt2 + predsS[(r0 + 3) * 3 + ch] * wgt3;
            const float* ip = img + ch * 4096;
            const float v00 = ip[y0 * 64 + x0], v01 = ip[y0 * 64 + x1];
            const float v10 = ip[y1 * 64 + x0], v11 = ip[y1 * 64 + x1];
            const float samp = v00 * (1.f - wy) * (1.f - wx) + v01 * (1.f - wy) * wx
                             + v10 * wy * (1.f - wx) + v11 * wy * wx;
            out[q * 3 + ch] = ret + samp;
        }
    }
}

// ---------------- launch ----------------

extern "C" void kernel_launch(void* const* d_in, const int* in_sizes, int n_in,
                              void* d_out, int out_size, void* d_ws, size_t ws_size,
                              hipStream_t stream) {
    const float* img   = (const float*)d_in[0];
    const float* coef  = (const float*)d_in[1];
    const float* freq  = (const float*)d_in[2];
    const float* coord = (const float*)d_in[3];
    const float* cell  = (const float*)d_in[4];
    const float* wcf   = (const float*)d_in[5];
    const float* wph   = (const float*)d_in[6];
    const float* w1    = (const float*)d_in[7];
    const float* b1    = (const float*)d_in[8];
    const float* w2    = (const float*)d_in[9];
    const float* b2    = (const float*)d_in[10];
    const float* w3    = (const float*)d_in[11];
    const float* b3    = (const float*)d_in[12];
    float* out = (float*)d_out;

    char* ws = (char*)d_ws;
    bf16_t* coefT = (bf16_t*)ws;                  // 4096*256*2 = 2,097,152
    bf16_t* freqT = (bf16_t*)(ws + 2097152);      // 4096*128*2 = 1,048,576
    bf16_t* w1b   = (bf16_t*)(ws + 3145728);      // 131,072
    bf16_t* w2b   = (bf16_t*)(ws + 3276800);      // 131,072
    float4* wtab  = (float4*)(ws + 3407872);      // 2,048

    transpose_cvt_kernel<<<dim3(128, 8), 256, 0, stream>>>(coef, coefT, 256);
    transpose_cvt_kernel<<<dim3(128, 4), 256, 0, stream>>>(freq, freqT, 128);
    cvt_w_kernel<<<256, 256, 0, stream>>>(w1, w2, w1b, w2b);
    pack_tab_kernel<<<1, 128, 0, stream>>>(wcf, wph, wtab);

    const size_t ldsBytes = 72704;  // 67584 buf + 3072 w3 + 512 area + 1536 preds
    lte_fused_kernel<<<Q / QPB, 512, ldsBytes, stream>>>(
        coefT, freqT, w1b, w2b, wtab, img, coord, cell, b1, b2, w3, b3, out);
}